// Round 5
// baseline (264.966 us; speedup 1.0000x reference)
//
#include <hip/hip_runtime.h>
#include <hip/hip_bf16.h>

// Problem constants (fixed by the reference)
#define B_   32
#define D_   3584
#define NH_  28
#define NKV_ 4
#define HD_  128
#define SW_  4096
#define GRP_ 7                    // NH/NKV
#define NQKV_ 4608                // (NH+2*NKV)*HD
#define SCALE_ 0.08838834764831845f  // HD^-0.5
#define NKC_ 16                   // split-K chunks for projections
#define KC_  224                  // D_/NKC_
#define NCHUNK_ 64                // attention s-chunks (grid = 32*4*64 = 8192 blocks)
#define CHUNK_ 64                 // SW_/NCHUNK_

// ---------------------------------------------------------------------------
// Split-K projection: P[kc][32][N] = X[32][3584] @ W[3584][N]  (partial sums)
// ---------------------------------------------------------------------------
__global__ __launch_bounds__(256) void proj_kernel(const float* __restrict__ X,
                                                   const float* __restrict__ W,
                                                   float* __restrict__ P, int N) {
    const int lane = threadIdx.x & 63;
    const int wv   = __builtin_amdgcn_readfirstlane(threadIdx.x >> 6);
    const int r0   = wv * 8;
    const int c2   = blockIdx.x * 64 + lane;   // float2 column index
    const int k0   = blockIdx.y * KC_;
    const int n2   = N >> 1;
    const float2* __restrict__ W2 = (const float2*)W;

    float2 acc[8];
#pragma unroll
    for (int i = 0; i < 8; ++i) acc[i] = make_float2(0.f, 0.f);

#pragma unroll 4
    for (int k = k0; k < k0 + KC_; ++k) {
        float2 w2 = W2[(size_t)k * n2 + c2];
#pragma unroll
        for (int i = 0; i < 8; ++i) {
            float xr = X[(size_t)(r0 + i) * D_ + k];   // wave-uniform -> s_load
            acc[i].x += xr * w2.x;
            acc[i].y += xr * w2.y;
        }
    }
    float2* P2 = (float2*)P;
#pragma unroll
    for (int i = 0; i < 8; ++i)
        P2[(size_t)(blockIdx.y * 32 + r0 + i) * n2 + c2] = acc[i];
}

// ---------------------------------------------------------------------------
// QKV finish: sum split-K partials + bias, RoPE (block-diag 2x2), q*scale.
// ---------------------------------------------------------------------------
__global__ __launch_bounds__(256) void qkv_finish(const float* __restrict__ P,
                                                  const float* __restrict__ bias,
                                                  const float* __restrict__ rot,
                                                  float* __restrict__ xqkv) {
    int t  = blockIdx.x * 256 + threadIdx.x;     // pair id, 32*2304 total
    int r  = t / (NQKV_ / 2);
    int cp = t - r * (NQKV_ / 2);
    int c0 = cp * 2;

    float v0 = bias[c0], v1 = bias[c0 + 1];
#pragma unroll
    for (int kc = 0; kc < NKC_; ++kc) {
        float2 pv = *(const float2*)&P[((size_t)(kc * 32 + r) * NQKV_) + c0];
        v0 += pv.x; v1 += pv.y;
    }
    if (c0 < (NH_ + NKV_) * HD_) {               // q and k sections get RoPE
        int j = (c0 & (HD_ - 1)) >> 1;           // head-local pair index
        float cs = rot[(2 * j) * HD_ + 2 * j];
        float sn = rot[(2 * j) * HD_ + 2 * j + 1];
        float o0 = v0 * cs - v1 * sn;
        float o1 = v0 * sn + v1 * cs;
        if (c0 < NH_ * HD_) { o0 *= SCALE_; o1 *= SCALE_; }   // fold q scale
        v0 = o0; v1 = o1;
    }
    *(float2*)&xqkv[(size_t)r * NQKV_ + c0] = make_float2(v0, v1);
}

// ---------------------------------------------------------------------------
// Flash-decode attention over one (b, kv, s-chunk of 64). No K in LDS:
// lanes 0-31 read the 32 contiguous quads of row r, lanes 32-63 of row r+1
// (fully coalesced), q quads live in registers, half-wave butterfly reduce
// produces row dots. Then per-head softmax, then R2-style coalesced PV.
// ---------------------------------------------------------------------------
__global__ __launch_bounds__(256) void attn_kernel(const float* __restrict__ xqkv,
                                                   const float* __restrict__ cache_k,
                                                   const float* __restrict__ cache_v,
                                                   const int* __restrict__ curp,
                                                   float* __restrict__ part_ctx,
                                                   float* __restrict__ part_ml) {
    __shared__ __align__(16) float sc[GRP_][CHUNK_];        // scores -> exp weights
    __shared__ __align__(16) float2 ctxbuf[4][GRP_ * 64];   // 14336 B

    const int bid  = blockIdx.x;
    const int c    = bid & (NCHUNK_ - 1);
    const int kv   = (bid >> 6) & (NKV_ - 1);
    const int b    = bid >> 8;
    const int tid  = threadIdx.x;
    const int lane = tid & 63;
    const int wv   = tid >> 6;
    const int hl   = lane & 31;      // lane within half-wave
    const int sub  = lane >> 5;      // which half (row parity)

    const int cur   = curp[0];
    const int slot  = cur & (SW_ - 1);
    const int sbase = c * CHUNK_;

    const float4* qg4   = (const float4*)(xqkv + (size_t)b * NQKV_ + kv * (GRP_ * HD_));
    const float4* knew4 = (const float4*)(xqkv + (size_t)b * NQKV_ + NH_ * HD_ + kv * HD_);
    const float4* kct4  = (const float4*)(cache_k + ((size_t)(b * NKV_ + kv) * SW_ + sbase) * HD_);

    // q quad for this lane, all 7 heads (28 VGPRs)
    float4 qreg[GRP_];
#pragma unroll
    for (int h = 0; h < GRP_; ++h) qreg[h] = qg4[h * 32 + hl];

    // ---- QK^T: wave w covers local rows [16w, 16w+16), 2 rows per iter ----
    const int rA = wv * 16;
#pragma unroll
    for (int i = 0; i < 8; ++i) {
        const int rl = rA + 2 * i + sub;       // local row this half covers
        const int gs = sbase + rl;             // global row
        const float4* kp = (gs == slot) ? (knew4 + hl)
                                        : (kct4 + (size_t)(rA + 2 * i) * 32 + lane);
        float4 kq = *kp;

        float part[GRP_];
#pragma unroll
        for (int h = 0; h < GRP_; ++h)
            part[h] = qreg[h].x * kq.x + qreg[h].y * kq.y
                    + qreg[h].z * kq.z + qreg[h].w * kq.w;
#pragma unroll
        for (int h = 0; h < GRP_; ++h) {
            part[h] += __shfl_xor(part[h], 1);
            part[h] += __shfl_xor(part[h], 2);
            part[h] += __shfl_xor(part[h], 4);
            part[h] += __shfl_xor(part[h], 8);
            part[h] += __shfl_xor(part[h], 16);
        }
        if (hl == 0) {
            const bool v = (gs <= cur);
#pragma unroll
            for (int h = 0; h < GRP_; ++h) sc[h][rl] = v ? part[h] : -1e30f;
        }
    }
    __syncthreads();

    // ---- softmax per head: wave w handles heads w and w+4 -----------------
    for (int h = wv; h < GRP_; h += 4) {
        float v = sc[h][lane];
        float m = v;
#pragma unroll
        for (int off = 32; off; off >>= 1) m = fmaxf(m, __shfl_xor(m, off));
        float e = __expf(v - m);
        sc[h][lane] = e;
        float s = e;
#pragma unroll
        for (int off = 32; off; off >>= 1) s += __shfl_xor(s, off);
        if (lane == 0) {
            part_ml[bid * 14 + h]     = m;
            part_ml[bid * 14 + 7 + h] = s;
        }
    }
    __syncthreads();

    // ---- PV: wave w owns rows [16w, 16w+16), coalesced float2 V reads -----
    const float2* vcb   = (const float2*)(cache_v + ((size_t)(b * NKV_ + kv) * SW_) * HD_);
    const float2* vnew2 = (const float2*)(xqkv + (size_t)b * NQKV_ + (NH_ + NKV_) * HD_ + kv * HD_);

    float2 acc2[GRP_];
#pragma unroll
    for (int h = 0; h < GRP_; ++h) acc2[h] = make_float2(0.f, 0.f);

    const int sA = wv * 16;
#pragma unroll 2
    for (int it = 0; it < 4; ++it) {
        int s = sA + it * 4;
        float2 vv[4];
#pragma unroll
        for (int r = 0; r < 4; ++r) {
            int gs = sbase + s + r;
            const float2* vp = (gs == slot) ? vnew2 : vcb + (size_t)gs * (HD_ / 2);
            vv[r] = vp[lane];
        }
#pragma unroll
        for (int h = 0; h < GRP_; ++h) {
            float4 pp = *(const float4*)&sc[h][s];
            acc2[h].x += pp.x * vv[0].x + pp.y * vv[1].x + pp.z * vv[2].x + pp.w * vv[3].x;
            acc2[h].y += pp.x * vv[0].y + pp.y * vv[1].y + pp.z * vv[2].y + pp.w * vv[3].y;
        }
    }

#pragma unroll
    for (int h = 0; h < GRP_; ++h)
        ctxbuf[wv][h * 64 + lane] = acc2[h];
    __syncthreads();

    // BUGFIX (R3/R4): GRP_*64 = 448 > blockDim 256 — must LOOP, not mask.
    // The single-shot `if (tid < 448)` left ctx elements 512..895 (heads 4-6)
    // unwritten every block -> deterministic absmax 0.11 in both rounds.
    float2* pc2 = (float2*)part_ctx;
    for (int t2 = tid; t2 < GRP_ * 64; t2 += 256) {
        float2 a = ctxbuf[0][t2], bb = ctxbuf[1][t2],
               cc2 = ctxbuf[2][t2], d = ctxbuf[3][t2];
        float2 r = make_float2(a.x + bb.x + cc2.x + d.x, a.y + bb.y + cc2.y + d.y);
        pc2[(size_t)bid * (GRP_ * 64) + t2] = r;
    }
}

// ---------------------------------------------------------------------------
// Combine the 64 chunk partials per (b, kv): flash-decoding rescale+normalize.
// ---------------------------------------------------------------------------
__global__ __launch_bounds__(256) void combine_kernel(const float* __restrict__ part_ctx,
                                                      const float* __restrict__ part_ml,
                                                      float* __restrict__ ctx) {
    const int g   = blockIdx.x;           // b*NKV + kv
    const int tid = threadIdx.x;
    __shared__ float fac[NCHUNK_][GRP_];

    if (tid < GRP_) {
        float M = -1e30f;
        for (int cc = 0; cc < NCHUNK_; ++cc)
            M = fmaxf(M, part_ml[(g * NCHUNK_ + cc) * 14 + tid]);
        float L = 0.f;
        for (int cc = 0; cc < NCHUNK_; ++cc) {
            float e = __expf(part_ml[(g * NCHUNK_ + cc) * 14 + tid] - M);
            fac[cc][tid] = e;
            L += part_ml[(g * NCHUNK_ + cc) * 14 + 7 + tid] * e;
        }
        float inv = 1.f / L;
        for (int cc = 0; cc < NCHUNK_; ++cc) fac[cc][tid] *= inv;
    }
    __syncthreads();

    const int b = g >> 2, kv = g & 3;
    for (int i = tid; i < GRP_ * HD_; i += 256) {
        int h = i >> 7;
        float s = 0.f;
#pragma unroll 8
        for (int cc = 0; cc < NCHUNK_; ++cc)
            s += part_ctx[(size_t)(g * NCHUNK_ + cc) * (GRP_ * HD_) + i] * fac[cc][h];
        ctx[(size_t)b * D_ + kv * (GRP_ * HD_) + i] = s;
    }
}

// ---------------------------------------------------------------------------
// Final reduce of O-projection split-K partials into d_out.
// ---------------------------------------------------------------------------
__global__ __launch_bounds__(256) void out_finish(const float* __restrict__ P,
                                                  float* __restrict__ out) {
    int t = blockIdx.x * 256 + threadIdx.x;   // < 32*3584
    float s = 0.f;
#pragma unroll
    for (int kc = 0; kc < NKC_; ++kc) s += P[(size_t)kc * (32 * D_) + t];
    out[t] = s;
}

// ---------------------------------------------------------------------------
extern "C" void kernel_launch(void* const* d_in, const int* in_sizes, int n_in,
                              void* d_out, int out_size, void* d_ws, size_t ws_size,
                              hipStream_t stream) {
    const float* x    = (const float*)d_in[0];
    const float* wqkv = (const float*)d_in[1];
    const float* bias = (const float*)d_in[2];
    const float* wo   = (const float*)d_in[3];
    const float* rot  = (const float*)d_in[4];
    const float* ck   = (const float*)d_in[5];
    const float* cv   = (const float*)d_in[6];
    const int*   cur  = (const int*)d_in[7];
    float* out = (float*)d_out;
    float* ws  = (float*)d_ws;

    // workspace layout (floats) — no aliasing, ~40 MB total
    float* partials = ws;                                        // 2,359,296
    float* xqkv     = partials + (size_t)NKC_ * 32 * NQKV_;      //   147,456
    float* pctx     = xqkv + (size_t)B_ * NQKV_;                 // 7,340,032
    float* pml      = pctx + (size_t)B_ * NKV_ * NCHUNK_ * GRP_ * HD_; // 114,688
    float* ctx      = pml  + (size_t)B_ * NKV_ * NCHUNK_ * 14;   //   114,688

    // 1) QKV projection (split-K partials)
    proj_kernel<<<dim3(NQKV_ / 128, NKC_), 256, 0, stream>>>(x, wqkv, partials, NQKV_);
    // 2) bias + RoPE + q-scale
    qkv_finish<<<(B_ * NQKV_ / 2) / 256, 256, 0, stream>>>(partials, bias, rot, xqkv);
    // 3) flash-decode attention over (b, kv, chunk)
    attn_kernel<<<B_ * NKV_ * NCHUNK_, 256, 0, stream>>>(xqkv, ck, cv, cur, pctx, pml);
    // 4) combine chunks
    combine_kernel<<<B_ * NKV_, 256, 0, stream>>>(pctx, pml, ctx);
    // 5) output projection (split-K partials, reuse buffer)
    proj_kernel<<<dim3(D_ / 128, NKC_), 256, 0, stream>>>(ctx, wo, partials, D_);
    // 6) reduce into d_out
    out_finish<<<(B_ * D_) / 256, 256, 0, stream>>>(partials, out);
}

// Round 6
// 227.397 us; speedup vs baseline: 1.1652x; 1.1652x over previous
//
#include <hip/hip_runtime.h>
#include <hip/hip_bf16.h>

// Problem constants (fixed by the reference)
#define B_   32
#define D_   3584
#define NH_  28
#define NKV_ 4
#define HD_  128
#define SW_  4096
#define GRP_ 7                    // NH/NKV
#define NQKV_ 4608                // (NH+2*NKV)*HD
#define SCALE_ 0.08838834764831845f  // HD^-0.5
#define NKC_ 16                   // split-K chunks for projections
#define KC_  224                  // D_/NKC_
#define NCHUNK_ 64                // attention s-chunks (grid = 32*4*64 = 8192 blocks)
#define CHUNK_ 64                 // SW_/NCHUNK_

// ---------------------------------------------------------------------------
// Split-K projection: P[kc][32][N] = X[32][3584] @ W[3584][N]  (partial sums)
// ---------------------------------------------------------------------------
__global__ __launch_bounds__(256) void proj_kernel(const float* __restrict__ X,
                                                   const float* __restrict__ W,
                                                   float* __restrict__ P, int N) {
    const int lane = threadIdx.x & 63;
    const int wv   = __builtin_amdgcn_readfirstlane(threadIdx.x >> 6);
    const int r0   = wv * 8;
    const int c2   = blockIdx.x * 64 + lane;   // float2 column index
    const int k0   = blockIdx.y * KC_;
    const int n2   = N >> 1;
    const float2* __restrict__ W2 = (const float2*)W;

    float2 acc[8];
#pragma unroll
    for (int i = 0; i < 8; ++i) acc[i] = make_float2(0.f, 0.f);

#pragma unroll 8
    for (int k = k0; k < k0 + KC_; ++k) {
        float2 w2 = W2[(size_t)k * n2 + c2];
#pragma unroll
        for (int i = 0; i < 8; ++i) {
            float xr = X[(size_t)(r0 + i) * D_ + k];   // wave-uniform -> s_load
            acc[i].x += xr * w2.x;
            acc[i].y += xr * w2.y;
        }
    }
    float2* P2 = (float2*)P;
#pragma unroll
    for (int i = 0; i < 8; ++i)
        P2[(size_t)(blockIdx.y * 32 + r0 + i) * n2 + c2] = acc[i];
}

// ---------------------------------------------------------------------------
// QKV finish: sum split-K partials + bias, RoPE (block-diag 2x2), q*scale.
// ---------------------------------------------------------------------------
__global__ __launch_bounds__(256) void qkv_finish(const float* __restrict__ P,
                                                  const float* __restrict__ bias,
                                                  const float* __restrict__ rot,
                                                  float* __restrict__ xqkv) {
    int t  = blockIdx.x * 256 + threadIdx.x;     // pair id, 32*2304 total
    int r  = t / (NQKV_ / 2);
    int cp = t - r * (NQKV_ / 2);
    int c0 = cp * 2;

    float v0 = bias[c0], v1 = bias[c0 + 1];
#pragma unroll
    for (int kc = 0; kc < NKC_; ++kc) {
        float2 pv = *(const float2*)&P[((size_t)(kc * 32 + r) * NQKV_) + c0];
        v0 += pv.x; v1 += pv.y;
    }
    if (c0 < (NH_ + NKV_) * HD_) {               // q and k sections get RoPE
        int j = (c0 & (HD_ - 1)) >> 1;           // head-local pair index
        float cs = rot[(2 * j) * HD_ + 2 * j];
        float sn = rot[(2 * j) * HD_ + 2 * j + 1];
        float o0 = v0 * cs - v1 * sn;
        float o1 = v0 * sn + v1 * cs;
        if (c0 < NH_ * HD_) { o0 *= SCALE_; o1 *= SCALE_; }   // fold q scale
        v0 = o0; v1 = o1;
    }
    *(float2*)&xqkv[(size_t)r * NQKV_ + c0] = make_float2(v0, v1);
}

// ---------------------------------------------------------------------------
// Flash-decode attention over one (b, kv, s-chunk of 64).
// R6: DEEP LOAD PIPELINING — all K quads (8) and V float2s (16) for this
// thread are issued up front into registers (~31 VMEM in flight/thread),
// then scores/softmax/PV run out of registers. Compute logic identical to
// the R5 kernel that passed.
// ---------------------------------------------------------------------------
__global__ __launch_bounds__(256) void attn_kernel(const float* __restrict__ xqkv,
                                                   const float* __restrict__ cache_k,
                                                   const float* __restrict__ cache_v,
                                                   const int* __restrict__ curp,
                                                   float* __restrict__ part_ctx,
                                                   float* __restrict__ part_ml) {
    __shared__ __align__(16) float sc[GRP_][CHUNK_];        // scores -> exp weights
    __shared__ __align__(16) float2 ctxbuf[4][GRP_ * 64];   // 14336 B

    const int bid  = blockIdx.x;
    const int c    = bid & (NCHUNK_ - 1);
    const int kv   = (bid >> 6) & (NKV_ - 1);
    const int b    = bid >> 8;
    const int tid  = threadIdx.x;
    const int lane = tid & 63;
    const int wv   = tid >> 6;
    const int hl   = lane & 31;      // lane within half-wave (quad index)
    const int sub  = lane >> 5;      // which half (row parity)

    const int cur   = curp[0];
    const int slot  = cur & (SW_ - 1);
    const int sbase = c * CHUNK_;

    const float4* qg4   = (const float4*)(xqkv + (size_t)b * NQKV_ + kv * (GRP_ * HD_));
    const float4* knew4 = (const float4*)(xqkv + (size_t)b * NQKV_ + NH_ * HD_ + kv * HD_);
    const float4* kct4  = (const float4*)(cache_k + ((size_t)(b * NKV_ + kv) * SW_ + sbase) * HD_);
    const float2* vcb   = (const float2*)(cache_v + ((size_t)(b * NKV_ + kv) * SW_) * HD_);
    const float2* vnew2 = (const float2*)(xqkv + (size_t)b * NQKV_ + (NH_ + NKV_) * HD_ + kv * HD_);

    const int rA = wv * 16;          // this wave's 16 rows (for QK^T and PV)

    // ---- issue ALL loads up front (q: 7, K: 8, V: 16 -> ~31 in flight) ----
    float4 qreg[GRP_];
#pragma unroll
    for (int h = 0; h < GRP_; ++h) qreg[h] = qg4[h * 32 + hl];

    float4 kq[8];
#pragma unroll
    for (int i = 0; i < 8; ++i) {
        const int gs = sbase + rA + 2 * i + sub;
        const float4* kp = (gs == slot) ? (knew4 + hl)
                                        : (kct4 + (size_t)(rA + 2 * i) * 32 + lane);
        kq[i] = *kp;
    }
    float2 vv[16];
#pragma unroll
    for (int r = 0; r < 16; ++r) {
        const int gsv = sbase + rA + r;
        const float2* vp = (gsv == slot) ? vnew2 : vcb + (size_t)gsv * (HD_ / 2);
        vv[r] = vp[lane];
    }

    // ---- QK^T from registers: 2 rows per iter, half-wave butterfly -------
#pragma unroll
    for (int i = 0; i < 8; ++i) {
        const int rl = rA + 2 * i + sub;       // local row this half covers
        const int gs = sbase + rl;

        float part[GRP_];
#pragma unroll
        for (int h = 0; h < GRP_; ++h)
            part[h] = qreg[h].x * kq[i].x + qreg[h].y * kq[i].y
                    + qreg[h].z * kq[i].z + qreg[h].w * kq[i].w;
#pragma unroll
        for (int h = 0; h < GRP_; ++h) {
            part[h] += __shfl_xor(part[h], 1);
            part[h] += __shfl_xor(part[h], 2);
            part[h] += __shfl_xor(part[h], 4);
            part[h] += __shfl_xor(part[h], 8);
            part[h] += __shfl_xor(part[h], 16);
        }
        if (hl == 0) {
            const bool v = (gs <= cur);
#pragma unroll
            for (int h = 0; h < GRP_; ++h) sc[h][rl] = v ? part[h] : -1e30f;
        }
    }
    __syncthreads();

    // ---- softmax per head: wave w handles heads w and w+4 -----------------
    for (int h = wv; h < GRP_; h += 4) {
        float v = sc[h][lane];
        float m = v;
#pragma unroll
        for (int off = 32; off; off >>= 1) m = fmaxf(m, __shfl_xor(m, off));
        float e = __expf(v - m);
        sc[h][lane] = e;
        float s = e;
#pragma unroll
        for (int off = 32; off; off >>= 1) s += __shfl_xor(s, off);
        if (lane == 0) {
            part_ml[bid * 14 + h]     = m;
            part_ml[bid * 14 + 7 + h] = s;
        }
    }
    __syncthreads();

    // ---- PV from preloaded registers: wave owns rows [rA, rA+16) ----------
    float2 acc2[GRP_];
#pragma unroll
    for (int h = 0; h < GRP_; ++h) acc2[h] = make_float2(0.f, 0.f);

#pragma unroll
    for (int it = 0; it < 4; ++it) {
        const int s = rA + it * 4;
#pragma unroll
        for (int h = 0; h < GRP_; ++h) {
            float4 pp = *(const float4*)&sc[h][s];
            acc2[h].x += pp.x * vv[it * 4 + 0].x + pp.y * vv[it * 4 + 1].x
                       + pp.z * vv[it * 4 + 2].x + pp.w * vv[it * 4 + 3].x;
            acc2[h].y += pp.x * vv[it * 4 + 0].y + pp.y * vv[it * 4 + 1].y
                       + pp.z * vv[it * 4 + 2].y + pp.w * vv[it * 4 + 3].y;
        }
    }

#pragma unroll
    for (int h = 0; h < GRP_; ++h)
        ctxbuf[wv][h * 64 + lane] = acc2[h];
    __syncthreads();

    // epilogue: strided LOOP over 448 float2 (R4 bugfix — keep as loop!)
    float2* pc2 = (float2*)part_ctx;
    for (int t2 = tid; t2 < GRP_ * 64; t2 += 256) {
        float2 a = ctxbuf[0][t2], bb = ctxbuf[1][t2],
               cc2 = ctxbuf[2][t2], d = ctxbuf[3][t2];
        float2 r = make_float2(a.x + bb.x + cc2.x + d.x, a.y + bb.y + cc2.y + d.y);
        pc2[(size_t)bid * (GRP_ * 64) + t2] = r;
    }
}

// ---------------------------------------------------------------------------
// Combine the 64 chunk partials: one block per (g, head); thread = column.
// ---------------------------------------------------------------------------
__global__ __launch_bounds__(128) void combine_kernel(const float* __restrict__ part_ctx,
                                                      const float* __restrict__ part_ml,
                                                      float* __restrict__ ctx) {
    const int g = blockIdx.x;             // b*NKV + kv
    const int h = blockIdx.y;             // head within group
    const int d = threadIdx.x;            // column 0..127

    float M = -1e30f;
    for (int cc = 0; cc < NCHUNK_; ++cc)
        M = fmaxf(M, part_ml[(g * NCHUNK_ + cc) * 14 + h]);   // uniform -> scalar

    float L = 0.f, s = 0.f;
    for (int cc = 0; cc < NCHUNK_; ++cc) {
        float e = __expf(part_ml[(g * NCHUNK_ + cc) * 14 + h] - M);
        L += part_ml[(g * NCHUNK_ + cc) * 14 + 7 + h] * e;
        s += part_ctx[(size_t)(g * NCHUNK_ + cc) * (GRP_ * HD_) + h * HD_ + d] * e;
    }
    const int b = g >> 2, kv = g & 3;
    ctx[(size_t)b * D_ + kv * (GRP_ * HD_) + h * HD_ + d] = s / L;
}

// ---------------------------------------------------------------------------
// Final reduce of O-projection split-K partials into d_out.
// ---------------------------------------------------------------------------
__global__ __launch_bounds__(256) void out_finish(const float* __restrict__ P,
                                                  float* __restrict__ out) {
    int t = blockIdx.x * 256 + threadIdx.x;   // < 32*3584
    float s = 0.f;
#pragma unroll
    for (int kc = 0; kc < NKC_; ++kc) s += P[(size_t)kc * (32 * D_) + t];
    out[t] = s;
}

// ---------------------------------------------------------------------------
extern "C" void kernel_launch(void* const* d_in, const int* in_sizes, int n_in,
                              void* d_out, int out_size, void* d_ws, size_t ws_size,
                              hipStream_t stream) {
    const float* x    = (const float*)d_in[0];
    const float* wqkv = (const float*)d_in[1];
    const float* bias = (const float*)d_in[2];
    const float* wo   = (const float*)d_in[3];
    const float* rot  = (const float*)d_in[4];
    const float* ck   = (const float*)d_in[5];
    const float* cv   = (const float*)d_in[6];
    const int*   cur  = (const int*)d_in[7];
    float* out = (float*)d_out;
    float* ws  = (float*)d_ws;

    // workspace layout (floats) — no aliasing, ~40 MB total
    float* partials = ws;                                        // 2,359,296
    float* xqkv     = partials + (size_t)NKC_ * 32 * NQKV_;      //   147,456
    float* pctx     = xqkv + (size_t)B_ * NQKV_;                 // 7,340,032
    float* pml      = pctx + (size_t)B_ * NKV_ * NCHUNK_ * GRP_ * HD_; // 114,688
    float* ctx      = pml  + (size_t)B_ * NKV_ * NCHUNK_ * 14;   //   114,688

    // 1) QKV projection (split-K partials)
    proj_kernel<<<dim3(NQKV_ / 128, NKC_), 256, 0, stream>>>(x, wqkv, partials, NQKV_);
    // 2) bias + RoPE + q-scale
    qkv_finish<<<(B_ * NQKV_ / 2) / 256, 256, 0, stream>>>(partials, bias, rot, xqkv);
    // 3) flash-decode attention over (b, kv, chunk)
    attn_kernel<<<B_ * NKV_ * NCHUNK_, 256, 0, stream>>>(xqkv, ck, cv, cur, pctx, pml);
    // 4) combine chunks — one block per (g, head)
    combine_kernel<<<dim3(B_ * NKV_, GRP_), 128, 0, stream>>>(pctx, pml, ctx);
    // 5) output projection (split-K partials, reuse buffer)
    proj_kernel<<<dim3(D_ / 128, NKC_), 256, 0, stream>>>(ctx, wo, partials, D_);
    // 6) reduce into d_out
    out_finish<<<(B_ * D_) / 256, 256, 0, stream>>>(partials, out);
}

// Round 7
// 201.013 us; speedup vs baseline: 1.3182x; 1.1313x over previous
//
#include <hip/hip_runtime.h>
#include <hip/hip_bf16.h>

// Problem constants (fixed by the reference)
#define B_   32
#define D_   3584
#define NH_  28
#define NKV_ 4
#define HD_  128
#define SW_  4096
#define GRP_ 7                    // NH/NKV
#define NQKV_ 4608                // (NH+2*NKV)*HD
#define SCALE_ 0.08838834764831845f  // HD^-0.5
#define NKC_ 16                   // split-K chunks for projections
#define KC_  224                  // D_/NKC_
#define NCHUNK_ 64                // attention s-chunks (grid = 32*4*64 = 8192 blocks)
#define CHUNK_ 64                 // SW_/NCHUNK_

// ---------------------------------------------------------------------------
// Half-wave (32-lane) all-reduce sum, VALU-DPP for 4 of 5 steps.
//  xor1: quad_perm(1,0,3,2)=0xB1   xor2: quad_perm(2,3,0,1)=0x4E
//  xor4: row_half_mirror 0x141 (== xor7; quads already uniform)
//  xor8: row_mirror      0x140 (== xor15; 8-groups already uniform)
//  xor16: ds_swizzle BitMode 0x401F (applies within each 32-lane group)
// ---------------------------------------------------------------------------
__device__ __forceinline__ float halfwave_allreduce(float x) {
    x += __int_as_float(__builtin_amdgcn_mov_dpp(__float_as_int(x), 0xB1, 0xF, 0xF, true));
    x += __int_as_float(__builtin_amdgcn_mov_dpp(__float_as_int(x), 0x4E, 0xF, 0xF, true));
    x += __int_as_float(__builtin_amdgcn_mov_dpp(__float_as_int(x), 0x141, 0xF, 0xF, true));
    x += __int_as_float(__builtin_amdgcn_mov_dpp(__float_as_int(x), 0x140, 0xF, 0xF, true));
    x += __int_as_float(__builtin_amdgcn_ds_swizzle(__float_as_int(x), 0x401F));
    return x;
}

// ---------------------------------------------------------------------------
// Split-K projection: P[kc][32][N] = X[32][3584] @ W[3584][N]  (partial sums)
// ---------------------------------------------------------------------------
__global__ __launch_bounds__(256) void proj_kernel(const float* __restrict__ X,
                                                   const float* __restrict__ W,
                                                   float* __restrict__ P, int N) {
    const int lane = threadIdx.x & 63;
    const int wv   = __builtin_amdgcn_readfirstlane(threadIdx.x >> 6);
    const int r0   = wv * 8;
    const int c2   = blockIdx.x * 64 + lane;   // float2 column index
    const int k0   = blockIdx.y * KC_;
    const int n2   = N >> 1;
    const float2* __restrict__ W2 = (const float2*)W;

    float2 acc[8];
#pragma unroll
    for (int i = 0; i < 8; ++i) acc[i] = make_float2(0.f, 0.f);

#pragma unroll 8
    for (int k = k0; k < k0 + KC_; ++k) {
        float2 w2 = W2[(size_t)k * n2 + c2];
#pragma unroll
        for (int i = 0; i < 8; ++i) {
            float xr = X[(size_t)(r0 + i) * D_ + k];   // wave-uniform -> s_load
            acc[i].x += xr * w2.x;
            acc[i].y += xr * w2.y;
        }
    }
    float2* P2 = (float2*)P;
#pragma unroll
    for (int i = 0; i < 8; ++i)
        P2[(size_t)(blockIdx.y * 32 + r0 + i) * n2 + c2] = acc[i];
}

// ---------------------------------------------------------------------------
// QKV finish: sum split-K partials + bias, RoPE (block-diag 2x2), q*scale.
// ---------------------------------------------------------------------------
__global__ __launch_bounds__(256) void qkv_finish(const float* __restrict__ P,
                                                  const float* __restrict__ bias,
                                                  const float* __restrict__ rot,
                                                  float* __restrict__ xqkv) {
    int t  = blockIdx.x * 256 + threadIdx.x;     // pair id, 32*2304 total
    int r  = t / (NQKV_ / 2);
    int cp = t - r * (NQKV_ / 2);
    int c0 = cp * 2;

    float v0 = bias[c0], v1 = bias[c0 + 1];
#pragma unroll
    for (int kc = 0; kc < NKC_; ++kc) {
        float2 pv = *(const float2*)&P[((size_t)(kc * 32 + r) * NQKV_) + c0];
        v0 += pv.x; v1 += pv.y;
    }
    if (c0 < (NH_ + NKV_) * HD_) {               // q and k sections get RoPE
        int j = (c0 & (HD_ - 1)) >> 1;           // head-local pair index
        float cs = rot[(2 * j) * HD_ + 2 * j];
        float sn = rot[(2 * j) * HD_ + 2 * j + 1];
        float o0 = v0 * cs - v1 * sn;
        float o1 = v0 * sn + v1 * cs;
        if (c0 < NH_ * HD_) { o0 *= SCALE_; o1 *= SCALE_; }   // fold q scale
        v0 = o0; v1 = o1;
    }
    *(float2*)&xqkv[(size_t)r * NQKV_ + c0] = make_float2(v0, v1);
}

// ---------------------------------------------------------------------------
// Flash-decode attention over one (b, kv, s-chunk of 64).
// R7: (a) __launch_bounds__(256,2) -> VGPR cap 128 so the up-front q/K/V
// loads (92 regs) genuinely stay in flight; (b) half-wave reduction via
// DPP (VALU pipe) instead of 5x ds_swizzle — DS ops per wave drop ~5x and
// the dependent-latency chain shrinks ~4x. All else identical to R6 (passed).
// ---------------------------------------------------------------------------
__global__ __launch_bounds__(256, 2) void attn_kernel(const float* __restrict__ xqkv,
                                                      const float* __restrict__ cache_k,
                                                      const float* __restrict__ cache_v,
                                                      const int* __restrict__ curp,
                                                      float* __restrict__ part_ctx,
                                                      float* __restrict__ part_ml) {
    __shared__ __align__(16) float sc[GRP_][CHUNK_];        // scores -> exp weights
    __shared__ __align__(16) float2 ctxbuf[4][GRP_ * 64];   // 14336 B

    const int bid  = blockIdx.x;
    const int c    = bid & (NCHUNK_ - 1);
    const int kv   = (bid >> 6) & (NKV_ - 1);
    const int b    = bid >> 8;
    const int tid  = threadIdx.x;
    const int lane = tid & 63;
    const int wv   = tid >> 6;
    const int hl   = lane & 31;      // lane within half-wave (quad index)
    const int sub  = lane >> 5;      // which half (row parity)

    const int cur   = curp[0];
    const int slot  = cur & (SW_ - 1);
    const int sbase = c * CHUNK_;

    const float4* qg4   = (const float4*)(xqkv + (size_t)b * NQKV_ + kv * (GRP_ * HD_));
    const float4* knew4 = (const float4*)(xqkv + (size_t)b * NQKV_ + NH_ * HD_ + kv * HD_);
    const float4* kct4  = (const float4*)(cache_k + ((size_t)(b * NKV_ + kv) * SW_ + sbase) * HD_);
    const float2* vcb   = (const float2*)(cache_v + ((size_t)(b * NKV_ + kv) * SW_) * HD_);
    const float2* vnew2 = (const float2*)(xqkv + (size_t)b * NQKV_ + (NH_ + NKV_) * HD_ + kv * HD_);

    const int rA = wv * 16;          // this wave's 16 rows (for QK^T and PV)

    // ---- issue ALL loads up front (q: 7, K: 8, V: 16 -> ~31 in flight) ----
    float4 qreg[GRP_];
#pragma unroll
    for (int h = 0; h < GRP_; ++h) qreg[h] = qg4[h * 32 + hl];

    float4 kq[8];
#pragma unroll
    for (int i = 0; i < 8; ++i) {
        const int gs = sbase + rA + 2 * i + sub;
        const float4* kp = (gs == slot) ? (knew4 + hl)
                                        : (kct4 + (size_t)(rA + 2 * i) * 32 + lane);
        kq[i] = *kp;
    }
    float2 vv[16];
#pragma unroll
    for (int r = 0; r < 16; ++r) {
        const int gsv = sbase + rA + r;
        const float2* vp = (gsv == slot) ? vnew2 : vcb + (size_t)gsv * (HD_ / 2);
        vv[r] = vp[lane];
    }

    // ---- QK^T from registers: 2 rows per iter, DPP half-wave reduce -------
#pragma unroll
    for (int i = 0; i < 8; ++i) {
        const int rl = rA + 2 * i + sub;       // local row this half covers
        const int gs = sbase + rl;

        float part[GRP_];
#pragma unroll
        for (int h = 0; h < GRP_; ++h)
            part[h] = qreg[h].x * kq[i].x + qreg[h].y * kq[i].y
                    + qreg[h].z * kq[i].z + qreg[h].w * kq[i].w;
#pragma unroll
        for (int h = 0; h < GRP_; ++h)
            part[h] = halfwave_allreduce(part[h]);
        if (hl == 0) {
            const bool v = (gs <= cur);
#pragma unroll
            for (int h = 0; h < GRP_; ++h) sc[h][rl] = v ? part[h] : -1e30f;
        }
    }
    __syncthreads();

    // ---- softmax per head: wave w handles heads w and w+4 -----------------
    for (int h = wv; h < GRP_; h += 4) {
        float v = sc[h][lane];
        float m = v;
#pragma unroll
        for (int off = 32; off; off >>= 1) m = fmaxf(m, __shfl_xor(m, off));
        float e = __expf(v - m);
        sc[h][lane] = e;
        float s = e;
#pragma unroll
        for (int off = 32; off; off >>= 1) s += __shfl_xor(s, off);
        if (lane == 0) {
            part_ml[bid * 14 + h]     = m;
            part_ml[bid * 14 + 7 + h] = s;
        }
    }
    __syncthreads();

    // ---- PV from preloaded registers: wave owns rows [rA, rA+16) ----------
    float2 acc2[GRP_];
#pragma unroll
    for (int h = 0; h < GRP_; ++h) acc2[h] = make_float2(0.f, 0.f);

#pragma unroll
    for (int it = 0; it < 4; ++it) {
        const int s = rA + it * 4;
#pragma unroll
        for (int h = 0; h < GRP_; ++h) {
            float4 pp = *(const float4*)&sc[h][s];
            acc2[h].x += pp.x * vv[it * 4 + 0].x + pp.y * vv[it * 4 + 1].x
                       + pp.z * vv[it * 4 + 2].x + pp.w * vv[it * 4 + 3].x;
            acc2[h].y += pp.x * vv[it * 4 + 0].y + pp.y * vv[it * 4 + 1].y
                       + pp.z * vv[it * 4 + 2].y + pp.w * vv[it * 4 + 3].y;
        }
    }

#pragma unroll
    for (int h = 0; h < GRP_; ++h)
        ctxbuf[wv][h * 64 + lane] = acc2[h];
    __syncthreads();

    // epilogue: strided LOOP over 448 float2 (R4 bugfix — keep as loop!)
    float2* pc2 = (float2*)part_ctx;
    for (int t2 = tid; t2 < GRP_ * 64; t2 += 256) {
        float2 a = ctxbuf[0][t2], bb = ctxbuf[1][t2],
               cc2 = ctxbuf[2][t2], d = ctxbuf[3][t2];
        float2 r = make_float2(a.x + bb.x + cc2.x + d.x, a.y + bb.y + cc2.y + d.y);
        pc2[(size_t)bid * (GRP_ * 64) + t2] = r;
    }
}

// ---------------------------------------------------------------------------
// Combine the 64 chunk partials: one block per (g, head); thread = column.
// ---------------------------------------------------------------------------
__global__ __launch_bounds__(128) void combine_kernel(const float* __restrict__ part_ctx,
                                                      const float* __restrict__ part_ml,
                                                      float* __restrict__ ctx) {
    const int g = blockIdx.x;             // b*NKV + kv
    const int h = blockIdx.y;             // head within group
    const int d = threadIdx.x;            // column 0..127

    float M = -1e30f;
    for (int cc = 0; cc < NCHUNK_; ++cc)
        M = fmaxf(M, part_ml[(g * NCHUNK_ + cc) * 14 + h]);   // uniform -> scalar

    float L = 0.f, s = 0.f;
    for (int cc = 0; cc < NCHUNK_; ++cc) {
        float e = __expf(part_ml[(g * NCHUNK_ + cc) * 14 + h] - M);
        L += part_ml[(g * NCHUNK_ + cc) * 14 + 7 + h] * e;
        s += part_ctx[(size_t)(g * NCHUNK_ + cc) * (GRP_ * HD_) + h * HD_ + d] * e;
    }
    const int b = g >> 2, kv = g & 3;
    ctx[(size_t)b * D_ + kv * (GRP_ * HD_) + h * HD_ + d] = s / L;
}

// ---------------------------------------------------------------------------
// Final reduce of O-projection split-K partials into d_out.
// ---------------------------------------------------------------------------
__global__ __launch_bounds__(256) void out_finish(const float* __restrict__ P,
                                                  float* __restrict__ out) {
    int t = blockIdx.x * 256 + threadIdx.x;   // < 32*3584
    float s = 0.f;
#pragma unroll
    for (int kc = 0; kc < NKC_; ++kc) s += P[(size_t)kc * (32 * D_) + t];
    out[t] = s;
}

// ---------------------------------------------------------------------------
extern "C" void kernel_launch(void* const* d_in, const int* in_sizes, int n_in,
                              void* d_out, int out_size, void* d_ws, size_t ws_size,
                              hipStream_t stream) {
    const float* x    = (const float*)d_in[0];
    const float* wqkv = (const float*)d_in[1];
    const float* bias = (const float*)d_in[2];
    const float* wo   = (const float*)d_in[3];
    const float* rot  = (const float*)d_in[4];
    const float* ck   = (const float*)d_in[5];
    const float* cv   = (const float*)d_in[6];
    const int*   cur  = (const int*)d_in[7];
    float* out = (float*)d_out;
    float* ws  = (float*)d_ws;

    // workspace layout (floats) — no aliasing, ~40 MB total
    float* partials = ws;                                        // 2,359,296
    float* xqkv     = partials + (size_t)NKC_ * 32 * NQKV_;      //   147,456
    float* pctx     = xqkv + (size_t)B_ * NQKV_;                 // 7,340,032
    float* pml      = pctx + (size_t)B_ * NKV_ * NCHUNK_ * GRP_ * HD_; // 114,688
    float* ctx      = pml  + (size_t)B_ * NKV_ * NCHUNK_ * 14;   //   114,688

    // 1) QKV projection (split-K partials)
    proj_kernel<<<dim3(NQKV_ / 128, NKC_), 256, 0, stream>>>(x, wqkv, partials, NQKV_);
    // 2) bias + RoPE + q-scale
    qkv_finish<<<(B_ * NQKV_ / 2) / 256, 256, 0, stream>>>(partials, bias, rot, xqkv);
    // 3) flash-decode attention over (b, kv, chunk)
    attn_kernel<<<B_ * NKV_ * NCHUNK_, 256, 0, stream>>>(xqkv, ck, cv, cur, pctx, pml);
    // 4) combine chunks — one block per (g, head)
    combine_kernel<<<dim3(B_ * NKV_, GRP_), 128, 0, stream>>>(pctx, pml, ctx);
    // 5) output projection (split-K partials, reuse buffer)
    proj_kernel<<<dim3(D_ / 128, NKC_), 256, 0, stream>>>(ctx, wo, partials, D_);
    // 6) reduce into d_out
    out_finish<<<(B_ * D_) / 256, 256, 0, stream>>>(partials, out);
}